// Round 4
// baseline (495.543 us; speedup 1.0000x reference)
//
#include <hip/hip_runtime.h>

// Fused LSTM(H=128) + MLP head, 16x16x32 bf16 MFMA, fp32 state.
// 512 blocks x 512 threads (8 waves), 16 rows/block -> 2 blocks/CU.
// Weights in VGPRs (112/wave, wave owns 16 hcols for all GEMMs).
// LDS A-panels stored in MFMA-fragment-contiguous order: every ds_read_b128
// is chunk_base + lane*16 (conflict-free, immediate offsets).
// Activations split bf16 hi+lo; fp32 accum/c/gates/head/feedback.
// 4 barriers/step; next-step feature loads prefetched behind z-GEMM.

#define T_STEPS 30
#define WARM_N  24
#define NT      512

typedef __attribute__((ext_vector_type(8))) short short8;   // 8 bf16
typedef __attribute__((ext_vector_type(4))) float floatx4;  // 16x16 C/D

struct FeatPtrs { const float* f[7]; };

__device__ __forceinline__ short f2bf(float f){
  unsigned u = __float_as_uint(f);
  return (short)((u + 0x7fffu + ((u >> 16) & 1u)) >> 16);
}
__device__ __forceinline__ float bf2f(short h){
  return __uint_as_float(((unsigned)(unsigned short)h) << 16);
}
__device__ __forceinline__ float sigm(float x){ return 1.0f/(1.0f + __expf(-x)); }
__device__ __forceinline__ float tanh_(float x){ return 1.0f - 2.0f/(__expf(2.0f*x) + 1.0f); }

// ---------------- weight pack (verified in round 3) ----------------
// 224 frags of 512 bf16. Frag (lane l, j): B[k=(l>>4)*8+j][n=colbase+(l&15)].
//  f 0..159   : z  [w 0..7][g 0..3][c 0..4]; c0 = x-chunk: k0..7=Wi, k8..15=Wi
//               (dup so merged [x_hi|x_lo] A does hi+lo in one MFMA), k16..31=0.
//               c1..4: Wh k-chunks of 32.
//  f 160..191 : W1 [w][c 0..3];  f 192..223 : W2 [w][c 0..3].
__global__ void pack_weights(const float* __restrict__ Wi, const float* __restrict__ Wh,
                             const float* __restrict__ W1, const float* __restrict__ W2,
                             short* __restrict__ ws)
{
  int idx = blockIdx.x * 256 + threadIdx.x;
  if (idx >= 224 * 512) return;
  int f = idx >> 9, r = idx & 511;
  int l = r >> 3, j = r & 7;
  int k   = ((l >> 4) << 3) + j;          // 0..31
  int n16 = l & 15;
  float v;
  if (f < 160){
    int w = f / 20, rem = f % 20, g = rem / 5, c = rem % 5;
    int col = g * 128 + w * 16 + n16;
    if (c == 0) v = (k < 8) ? Wi[k * 512 + col]
                : (k < 16) ? Wi[(k - 8) * 512 + col] : 0.0f;
    else        v = Wh[((c - 1) * 32 + k) * 512 + col];
  } else if (f < 192){
    int f2 = f - 160, w = f2 >> 2, c = f2 & 3;
    v = W1[(c * 32 + k) * 128 + w * 16 + n16];
  } else {
    int f2 = f - 192, w = f2 >> 2, c = f2 & 3;
    v = W2[(c * 32 + k) * 128 + w * 16 + n16];
  }
  ws[idx] = f2bf(v);
}

// ---------------- main kernel ----------------
// fragment offset within a 512-short chunk: ((k>>3)*16 + m)*8 + (k&7)
__global__ __launch_bounds__(NT, 4)
void lstm_mfma(FeatPtrs fp, const float* __restrict__ irr,
               const short* __restrict__ wsb,
               const float* __restrict__ bz, const float* __restrict__ b1,
               const float* __restrict__ b2, const float* __restrict__ Wout,
               const float* __restrict__ bout, float* __restrict__ out)
{
  __shared__ __align__(16) short xp[512];          // x chunk: k0-7 hi, 8-15 lo, 16-31 zero
  __shared__ __align__(16) short hp[2][8][512];    // [parity][c: 0..3 hi, 4..7 lo]
  __shared__ __align__(16) short o1p[4][512];
  __shared__ float part[16][9];                    // head partials [row][wave]

  const int t    = threadIdx.x;
  const int l    = t & 63;
  const int w    = t >> 6;          // 0..7
  const int c15  = l & 15;
  const int quad = l >> 4;          // 0..3
  const int hcol = w * 16 + c15;
  const int kc   = hcol & 31;       // k within chunk for activation writes
  const int chk  = hcol >> 5;       // destination chunk
  const int woff = ((kc >> 3) * 16) * 8 + (kc & 7) + quad * 32; // + q*8 later
  const int r0   = blockIdx.x * 16;

  // weight fragments -> registers (coalesced)
  short8 Bz[4][5], B1f[4], B2f[4];
  {
    const short8* f8 = (const short8*)wsb;
#pragma unroll
    for (int g = 0; g < 4; ++g)
#pragma unroll
      for (int c = 0; c < 5; ++c)
        Bz[g][c] = f8[((w * 4 + g) * 5 + c) * 64 + l];
#pragma unroll
    for (int c = 0; c < 4; ++c) B1f[c] = f8[(160 + w * 4 + c) * 64 + l];
#pragma unroll
    for (int c = 0; c < 4; ++c) B2f[c] = f8[(192 + w * 4 + c) * 64 + l];
  }
  float bzv[4];
#pragma unroll
  for (int g = 0; g < 4; ++g) bzv[g] = bz[g * 128 + hcol];
  const float b1v = b1[hcol], b2v = b2[hcol];
  const float woutv = Wout[hcol];
  const float bout0 = bout[0];

  { // zero hp[parity 0] (h0=0) and xp zero-pad region (k16..31)
    int* p = (int*)&hp[0][0][0];
    for (int i = t; i < 2048; i += NT) p[i] = 0;
    if (t < 128) ((int*)xp)[128 + t] = 0;
  }
  float cst[4];
#pragma unroll
  for (int q = 0; q < 4; ++q) cst[q] = 0.0f;

  const int gr = t >> 3, gj = t & 7;     // gather role (t < 128)
  float fnext = 0.0f;
  if (t < 128 && gj < 7) fnext = fp.f[gj][(r0 + gr) * T_STEPS];
  __syncthreads();

  for (int step = 0; step < T_STEPS; ++step){
    // ---- gather inputs + deferred head output ----
    if (t < 128){
      float v;
      if (gj == 7){
        if (step > 0){
          float p = part[gr][0] + part[gr][1] + part[gr][2] + part[gr][3]
                  + part[gr][4] + part[gr][5] + part[gr][6] + part[gr][7] + bout0;
          out[(r0 + gr) * T_STEPS + (step - 1)] = p;
          v = (step < WARM_N) ? irr[(r0 + gr) * WARM_N + step] : p;
        } else {
          v = irr[(r0 + gr) * WARM_N];
        }
      } else {
        v = fnext;
      }
      short hi = f2bf(v);
      xp[gr * 8 + gj]       = hi;                    // k = gj      (hi)
      xp[128 + gr * 8 + gj] = f2bf(v - bf2f(hi));    // k = 8 + gj  (lo)
    }
    __syncthreads();                                  // B1

    // prefetch next step's features (latency hidden behind z-GEMM)
    if (t < 128 && gj < 7 && step + 1 < T_STEPS)
      fnext = fp.f[gj][(r0 + gr) * T_STEPS + step + 1];

    const int rp = step & 1, wp = rp ^ 1;

    // ---- z = b + [x_hi|x_lo]@[Wi;Wi] + (h_hi+h_lo)@Wh ----
    floatx4 acc[4];
#pragma unroll
    for (int g = 0; g < 4; ++g)
#pragma unroll
      for (int q = 0; q < 4; ++q) acc[g][q] = bzv[g];
    {
      short8 ax = *(const short8*)&xp[l * 8];
#pragma unroll
      for (int g = 0; g < 4; ++g)
        acc[g] = __builtin_amdgcn_mfma_f32_16x16x32_bf16(ax, Bz[g][0], acc[g], 0, 0, 0);
    }
#pragma unroll
    for (int c = 0; c < 4; ++c){
      short8 ah = *(const short8*)&hp[rp][c][l * 8];
      short8 al = *(const short8*)&hp[rp][4 + c][l * 8];
#pragma unroll
      for (int g = 0; g < 4; ++g){
        acc[g] = __builtin_amdgcn_mfma_f32_16x16x32_bf16(ah, Bz[g][1 + c], acc[g], 0, 0, 0);
        acc[g] = __builtin_amdgcn_mfma_f32_16x16x32_bf16(al, Bz[g][1 + c], acc[g], 0, 0, 0);
      }
    }

    // ---- gates (fp32 in-lane), c update, h write (parity wp) ----
#pragma unroll
    for (int q = 0; q < 4; ++q){
      float zi = acc[0][q], zf = acc[1][q], zg = acc[2][q], zo = acc[3][q];
      float c2 = sigm(zf) * cst[q] + sigm(zi) * tanh_(zg);
      cst[q] = c2;
      float h2 = sigm(zo) * tanh_(c2);
      short hi = f2bf(h2);
      hp[wp][chk][woff + q * 8]     = hi;
      hp[wp][4 + chk][woff + q * 8] = f2bf(h2 - bf2f(hi));
    }
    __syncthreads();                                  // B2

    // ---- MLP1: o1 = relu(h@W1 + b1) ----
    floatx4 m1;
#pragma unroll
    for (int q = 0; q < 4; ++q) m1[q] = b1v;
#pragma unroll
    for (int c = 0; c < 4; ++c){
      short8 ah = *(const short8*)&hp[wp][c][l * 8];
      m1 = __builtin_amdgcn_mfma_f32_16x16x32_bf16(ah, B1f[c], m1, 0, 0, 0);
      short8 al = *(const short8*)&hp[wp][4 + c][l * 8];
      m1 = __builtin_amdgcn_mfma_f32_16x16x32_bf16(al, B1f[c], m1, 0, 0, 0);
    }
#pragma unroll
    for (int q = 0; q < 4; ++q)
      o1p[chk][woff + q * 8] = f2bf(fmaxf(m1[q], 0.0f));
    __syncthreads();                                  // B3

    // ---- MLP2 + head partials ----
    floatx4 m2;
#pragma unroll
    for (int q = 0; q < 4; ++q) m2[q] = b2v;
#pragma unroll
    for (int c = 0; c < 4; ++c){
      short8 a = *(const short8*)&o1p[c][l * 8];
      m2 = __builtin_amdgcn_mfma_f32_16x16x32_bf16(a, B2f[c], m2, 0, 0, 0);
    }
#pragma unroll
    for (int q = 0; q < 4; ++q){
      float s = fmaxf(m2[q], 0.0f) * woutv;           // o2[row][hcol] * Wout[hcol]
      s += __shfl_down(s, 8, 16);
      s += __shfl_down(s, 4, 16);
      s += __shfl_down(s, 2, 16);
      s += __shfl_down(s, 1, 16);
      if (c15 == 0) part[quad * 4 + q][w] = s;
    }
    __syncthreads();                                  // B4
  }

  // ---- final step's head output ----
  if (t < 16){
    float p = part[t][0] + part[t][1] + part[t][2] + part[t][3]
            + part[t][4] + part[t][5] + part[t][6] + part[t][7] + bout0;
    out[(r0 + t) * T_STEPS + (T_STEPS - 1)] = p;
  }
}

extern "C" void kernel_launch(void* const* d_in, const int* in_sizes, int n_in,
                              void* d_out, int out_size, void* d_ws, size_t ws_size,
                              hipStream_t stream)
{
  (void)in_sizes; (void)n_in; (void)out_size; (void)ws_size;
  FeatPtrs fp;
  for (int j = 0; j < 7; ++j) fp.f[j] = (const float*)d_in[8 + j];
  const float* irr  = (const float*)d_in[15];
  const float* Wi   = (const float*)d_in[16];
  const float* Wh   = (const float*)d_in[17];
  const float* bz   = (const float*)d_in[18];
  const float* W1   = (const float*)d_in[19];
  const float* b1   = (const float*)d_in[20];
  const float* W2   = (const float*)d_in[21];
  const float* b2   = (const float*)d_in[22];
  const float* Wout = (const float*)d_in[23];
  const float* bout = (const float*)d_in[24];

  short* ws = (short*)d_ws;                        // 224 KB used
  pack_weights<<<dim3(448), dim3(256), 0, stream>>>(Wi, Wh, W1, W2, ws);
  lstm_mfma<<<dim3(512), dim3(NT), 0, stream>>>(
      fp, irr, ws, bz, b1, b2, Wout, bout, (float*)d_out);
}

// Round 5
// 316.249 us; speedup vs baseline: 1.5669x; 1.5669x over previous
//
#include <hip/hip_runtime.h>

// Fused LSTM(H=128) + MLP head, 16x16x32 bf16 MFMA, fp32 state.
// 512 blocks x 512 threads (8 waves), 16 rows/block -> 2 blocks/CU.
// Register budget: ONLY z-weights (Wi/Wh) live in VGPRs (80 regs); W1/W2
// fragments live in LDS (64 KB) and are read as lane-linear ds_read_b128.
// VGPR target ~120 < 128 cap from __launch_bounds__(512,4) -> no spill.
// LDS ~77.6 KB/block -> 2 blocks/CU. Single h panel (no parity) + 5
// barriers/step. Fragment-contiguous LDS layout (conflict-free reads).
// Activations split bf16 hi+lo; fp32 accum/c/gates/head/feedback.

#define T_STEPS 30
#define WARM_N  24
#define NT      512

typedef __attribute__((ext_vector_type(8))) short short8;   // 8 bf16
typedef __attribute__((ext_vector_type(4))) float floatx4;  // 16x16 C/D

struct FeatPtrs { const float* f[7]; };

__device__ __forceinline__ short f2bf(float f){
  unsigned u = __float_as_uint(f);
  return (short)((u + 0x7fffu + ((u >> 16) & 1u)) >> 16);
}
__device__ __forceinline__ float bf2f(short h){
  return __uint_as_float(((unsigned)(unsigned short)h) << 16);
}
__device__ __forceinline__ float sigm(float x){ return 1.0f/(1.0f + __expf(-x)); }
__device__ __forceinline__ float tanh_(float x){ return 1.0f - 2.0f/(__expf(2.0f*x) + 1.0f); }

// ---------------- weight pack (unchanged, verified rounds 3-4) ----------------
// 224 frags of 512 bf16. Frag (lane l, j): B[k=(l>>4)*8+j][n=colbase+(l&15)].
//  f 0..159   : z  [w 0..7][g 0..3][c 0..4]; c0 = x-chunk: k0..7=Wi, k8..15=Wi
//               (dup so merged [x_hi|x_lo] A does hi+lo in one MFMA), k16..31=0.
//               c1..4: Wh k-chunks of 32.
//  f 160..191 : W1 [w][c 0..3];  f 192..223 : W2 [w][c 0..3].
__global__ void pack_weights(const float* __restrict__ Wi, const float* __restrict__ Wh,
                             const float* __restrict__ W1, const float* __restrict__ W2,
                             short* __restrict__ ws)
{
  int idx = blockIdx.x * 256 + threadIdx.x;
  if (idx >= 224 * 512) return;
  int f = idx >> 9, r = idx & 511;
  int l = r >> 3, j = r & 7;
  int k   = ((l >> 4) << 3) + j;          // 0..31
  int n16 = l & 15;
  float v;
  if (f < 160){
    int w = f / 20, rem = f % 20, g = rem / 5, c = rem % 5;
    int col = g * 128 + w * 16 + n16;
    if (c == 0) v = (k < 8) ? Wi[k * 512 + col]
                : (k < 16) ? Wi[(k - 8) * 512 + col] : 0.0f;
    else        v = Wh[((c - 1) * 32 + k) * 512 + col];
  } else if (f < 192){
    int f2 = f - 160, w = f2 >> 2, c = f2 & 3;
    v = W1[(c * 32 + k) * 128 + w * 16 + n16];
  } else {
    int f2 = f - 192, w = f2 >> 2, c = f2 & 3;
    v = W2[(c * 32 + k) * 128 + w * 16 + n16];
  }
  ws[idx] = f2bf(v);
}

// ---------------- main kernel ----------------
// fragment offset within a 512-short chunk: ((k>>3)*16 + m)*8 + (k&7)
__global__ __launch_bounds__(NT, 4)
void lstm_mfma(FeatPtrs fp, const float* __restrict__ irr,
               const short* __restrict__ wsb,
               const float* __restrict__ bz, const float* __restrict__ b1,
               const float* __restrict__ b2, const float* __restrict__ Wout,
               const float* __restrict__ bout, float* __restrict__ out)
{
  __shared__ __align__(16) short xp[512];        // x chunk: k0-7 hi, 8-15 lo, 16-31 zero
  __shared__ __align__(16) short hp[8][512];     // h panels [c: 0..3 hi, 4..7 lo]
  __shared__ __align__(16) short o1p[4][512];
  __shared__ __align__(16) short wmf[32768];     // W1 frags [0..16383], W2 [16384..]
  __shared__ float part[16][9];                  // head partials [row][wave]

  const int t    = threadIdx.x;
  const int l    = t & 63;
  const int w    = t >> 6;          // 0..7
  const int c15  = l & 15;
  const int quad = l >> 4;          // 0..3
  const int hcol = w * 16 + c15;
  const int kc   = hcol & 31;       // k within chunk for activation writes
  const int chk  = hcol >> 5;       // destination chunk
  const int woff = ((kc >> 3) * 16) * 8 + (kc & 7) + quad * 32; // + q*8 later
  const int r0   = blockIdx.x * 16;

  // z-weight fragments -> registers (80 VGPRs); W1/W2 -> LDS
  short8 Bz[4][5];
  {
    const short8* f8 = (const short8*)wsb;
#pragma unroll
    for (int g = 0; g < 4; ++g)
#pragma unroll
      for (int c = 0; c < 5; ++c)
        Bz[g][c] = f8[((w * 4 + g) * 5 + c) * 64 + l];
    // copy frags 160..223 (64 KB) into LDS, linear
    short8* wm8 = (short8*)wmf;
#pragma unroll
    for (int i = 0; i < 8; ++i)
      wm8[t + i * NT] = f8[160 * 64 + t + i * NT];
  }
  float bzv[4];
#pragma unroll
  for (int g = 0; g < 4; ++g) bzv[g] = bz[g * 128 + hcol];
  const float b1v = b1[hcol], b2v = b2[hcol];
  const float woutv = Wout[hcol];
  const float bout0 = bout[0];

  { // zero hp (h0=0) and xp zero-pad region (k16..31)
    int* p = (int*)&hp[0][0];
    for (int i = t; i < 2048; i += NT) p[i] = 0;
    if (t < 128) ((int*)xp)[128 + t] = 0;
  }
  float cst[4];
#pragma unroll
  for (int q = 0; q < 4; ++q) cst[q] = 0.0f;

  const int gr = t >> 3, gj = t & 7;     // gather role (t < 128)
  __syncthreads();

  for (int step = 0; step < T_STEPS; ++step){
    // ---- gather inputs + deferred head output (p of step-1) ----
    if (t < 128){
      float v;
      if (gj == 7){
        if (step > 0){
          float p = part[gr][0] + part[gr][1] + part[gr][2] + part[gr][3]
                  + part[gr][4] + part[gr][5] + part[gr][6] + part[gr][7] + bout0;
          out[(r0 + gr) * T_STEPS + (step - 1)] = p;
          v = (step < WARM_N) ? irr[(r0 + gr) * WARM_N + step] : p;
        } else {
          v = irr[(r0 + gr) * WARM_N];
        }
      } else {
        v = fp.f[gj][(r0 + gr) * T_STEPS + step];
      }
      short hi = f2bf(v);
      xp[gr * 8 + gj]       = hi;                    // k = gj      (hi)
      xp[128 + gr * 8 + gj] = f2bf(v - bf2f(hi));    // k = 8 + gj  (lo)
    }
    __syncthreads();                                  // B1: xp visible

    // ---- z = b + [x_hi|x_lo]@[Wi;Wi] + (h_hi+h_lo)@Wh ----
    floatx4 acc[4];
#pragma unroll
    for (int g = 0; g < 4; ++g)
#pragma unroll
      for (int q = 0; q < 4; ++q) acc[g][q] = bzv[g];
    {
      short8 ax = *(const short8*)&xp[l * 8];
#pragma unroll
      for (int g = 0; g < 4; ++g)
        acc[g] = __builtin_amdgcn_mfma_f32_16x16x32_bf16(ax, Bz[g][0], acc[g], 0, 0, 0);
    }
#pragma unroll
    for (int c = 0; c < 4; ++c){
      short8 ah = *(const short8*)&hp[c][l * 8];
      short8 al = *(const short8*)&hp[4 + c][l * 8];
#pragma unroll
      for (int g = 0; g < 4; ++g){
        acc[g] = __builtin_amdgcn_mfma_f32_16x16x32_bf16(ah, Bz[g][1 + c], acc[g], 0, 0, 0);
        acc[g] = __builtin_amdgcn_mfma_f32_16x16x32_bf16(al, Bz[g][1 + c], acc[g], 0, 0, 0);
      }
    }
    __syncthreads();                                  // B2: all h reads done (WAR)

    // ---- gates (fp32 in-lane), c update, h write in place ----
#pragma unroll
    for (int q = 0; q < 4; ++q){
      float zi = acc[0][q], zf = acc[1][q], zg = acc[2][q], zo = acc[3][q];
      float c2 = sigm(zf) * cst[q] + sigm(zi) * tanh_(zg);
      cst[q] = c2;
      float h2 = sigm(zo) * tanh_(c2);
      short hi = f2bf(h2);
      hp[chk][woff + q * 8]     = hi;
      hp[4 + chk][woff + q * 8] = f2bf(h2 - bf2f(hi));
    }
    __syncthreads();                                  // B3: new h visible

    // ---- MLP1: o1 = relu(h@W1 + b1), W1 frags from LDS ----
    floatx4 m1;
#pragma unroll
    for (int q = 0; q < 4; ++q) m1[q] = b1v;
#pragma unroll
    for (int c = 0; c < 4; ++c){
      short8 bf = *(const short8*)&wmf[(w * 4 + c) * 512 + l * 8];
      short8 ah = *(const short8*)&hp[c][l * 8];
      m1 = __builtin_amdgcn_mfma_f32_16x16x32_bf16(ah, bf, m1, 0, 0, 0);
      short8 al = *(const short8*)&hp[4 + c][l * 8];
      m1 = __builtin_amdgcn_mfma_f32_16x16x32_bf16(al, bf, m1, 0, 0, 0);
    }
#pragma unroll
    for (int q = 0; q < 4; ++q)
      o1p[chk][woff + q * 8] = f2bf(fmaxf(m1[q], 0.0f));
    __syncthreads();                                  // B4: o1 visible

    // ---- MLP2 + head partials, W2 frags from LDS ----
    floatx4 m2;
#pragma unroll
    for (int q = 0; q < 4; ++q) m2[q] = b2v;
#pragma unroll
    for (int c = 0; c < 4; ++c){
      short8 bf = *(const short8*)&wmf[16384 + (w * 4 + c) * 512 + l * 8];
      short8 a = *(const short8*)&o1p[c][l * 8];
      m2 = __builtin_amdgcn_mfma_f32_16x16x32_bf16(a, bf, m2, 0, 0, 0);
    }
#pragma unroll
    for (int q = 0; q < 4; ++q){
      float s = fmaxf(m2[q], 0.0f) * woutv;           // o2[row][hcol] * Wout[hcol]
      s += __shfl_down(s, 8, 16);
      s += __shfl_down(s, 4, 16);
      s += __shfl_down(s, 2, 16);
      s += __shfl_down(s, 1, 16);
      if (c15 == 0) part[quad * 4 + q][w] = s;
    }
    __syncthreads();                                  // B5: part visible
  }

  // ---- final step's head output ----
  if (t < 16){
    float p = part[t][0] + part[t][1] + part[t][2] + part[t][3]
            + part[t][4] + part[t][5] + part[t][6] + part[t][7] + bout0;
    out[(r0 + t) * T_STEPS + (T_STEPS - 1)] = p;
  }
}

extern "C" void kernel_launch(void* const* d_in, const int* in_sizes, int n_in,
                              void* d_out, int out_size, void* d_ws, size_t ws_size,
                              hipStream_t stream)
{
  (void)in_sizes; (void)n_in; (void)out_size; (void)ws_size;
  FeatPtrs fp;
  for (int j = 0; j < 7; ++j) fp.f[j] = (const float*)d_in[8 + j];
  const float* irr  = (const float*)d_in[15];
  const float* Wi   = (const float*)d_in[16];
  const float* Wh   = (const float*)d_in[17];
  const float* bz   = (const float*)d_in[18];
  const float* W1   = (const float*)d_in[19];
  const float* b1   = (const float*)d_in[20];
  const float* W2   = (const float*)d_in[21];
  const float* b2   = (const float*)d_in[22];
  const float* Wout = (const float*)d_in[23];
  const float* bout = (const float*)d_in[24];

  short* ws = (short*)d_ws;                        // 224 KB used
  pack_weights<<<dim3(448), dim3(256), 0, stream>>>(Wi, Wh, W1, W2, ws);
  lstm_mfma<<<dim3(512), dim3(NT), 0, stream>>>(
      fp, irr, ws, bz, b1, b2, Wout, bout, (float*)d_out);
}

// Round 6
// 304.611 us; speedup vs baseline: 1.6268x; 1.0382x over previous
//
#include <hip/hip_runtime.h>

// Fused LSTM(H=128) + MLP head, 16x16x32 bf16 MFMA, fp32 state.
// 512 blocks x 512 threads (8 waves), 16 rows/block -> 2 blocks/CU.
// z-weights (Wi/Wh) in VGPRs (80 regs/wave); W1/W2 fragments in LDS (64 KB),
// read as lane-linear conflict-free ds_read_b128.
// __launch_bounds__(512, 2): rounds 4-5 proved min-waves=4 poisons the
// allocator (VGPR_Count=64 + 300-915 MB scratch spill traffic); bounds=2
// gave 124 regs / no spill in round 3. HW still co-schedules 2 blocks/CU
// when actual VGPR <= 128 and LDS <= 80 KB.
// LDS ~78 KB/block. 5 barriers/step. Fragment-contiguous panels.
// Activations split bf16 hi+lo; fp32 accum/c/gates/head/feedback.

#define T_STEPS 30
#define WARM_N  24
#define NT      512

typedef __attribute__((ext_vector_type(8))) short short8;   // 8 bf16
typedef __attribute__((ext_vector_type(4))) float floatx4;  // 16x16 C/D

struct FeatPtrs { const float* f[7]; };

__device__ __forceinline__ short f2bf(float f){
  unsigned u = __float_as_uint(f);
  return (short)((u + 0x7fffu + ((u >> 16) & 1u)) >> 16);
}
__device__ __forceinline__ float bf2f(short h){
  return __uint_as_float(((unsigned)(unsigned short)h) << 16);
}
__device__ __forceinline__ float sigm(float x){ return 1.0f/(1.0f + __expf(-x)); }
__device__ __forceinline__ float tanh_(float x){ return 1.0f - 2.0f/(__expf(2.0f*x) + 1.0f); }

// ---------------- weight pack (unchanged, verified rounds 3-5) ----------------
// 224 frags of 512 bf16. Frag (lane l, j): B[k=(l>>4)*8+j][n=colbase+(l&15)].
//  f 0..159   : z  [w 0..7][g 0..3][c 0..4]; c0 = x-chunk: k0..7=Wi, k8..15=Wi
//               (dup so merged [x_hi|x_lo] A does hi+lo in one MFMA), k16..31=0.
//               c1..4: Wh k-chunks of 32.
//  f 160..191 : W1 [w][c 0..3];  f 192..223 : W2 [w][c 0..3].
__global__ void pack_weights(const float* __restrict__ Wi, const float* __restrict__ Wh,
                             const float* __restrict__ W1, const float* __restrict__ W2,
                             short* __restrict__ ws)
{
  int idx = blockIdx.x * 256 + threadIdx.x;
  if (idx >= 224 * 512) return;
  int f = idx >> 9, r = idx & 511;
  int l = r >> 3, j = r & 7;
  int k   = ((l >> 4) << 3) + j;          // 0..31
  int n16 = l & 15;
  float v;
  if (f < 160){
    int w = f / 20, rem = f % 20, g = rem / 5, c = rem % 5;
    int col = g * 128 + w * 16 + n16;
    if (c == 0) v = (k < 8) ? Wi[k * 512 + col]
                : (k < 16) ? Wi[(k - 8) * 512 + col] : 0.0f;
    else        v = Wh[((c - 1) * 32 + k) * 512 + col];
  } else if (f < 192){
    int f2 = f - 160, w = f2 >> 2, c = f2 & 3;
    v = W1[(c * 32 + k) * 128 + w * 16 + n16];
  } else {
    int f2 = f - 192, w = f2 >> 2, c = f2 & 3;
    v = W2[(c * 32 + k) * 128 + w * 16 + n16];
  }
  ws[idx] = f2bf(v);
}

// ---------------- main kernel ----------------
// fragment offset within a 512-short chunk: ((k>>3)*16 + m)*8 + (k&7)
__global__ __launch_bounds__(NT, 2)
void lstm_mfma(FeatPtrs fp, const float* __restrict__ irr,
               const short* __restrict__ wsb,
               const float* __restrict__ bz, const float* __restrict__ b1,
               const float* __restrict__ b2, const float* __restrict__ Wout,
               const float* __restrict__ bout, float* __restrict__ out)
{
  __shared__ __align__(16) short xp[512];        // x chunk: k0-7 hi, 8-15 lo, 16-31 zero
  __shared__ __align__(16) short hp[8][512];     // h panels [c: 0..3 hi, 4..7 lo]
  __shared__ __align__(16) short o1p[4][512];
  __shared__ __align__(16) short wmf[32768];     // W1 frags [0..16383], W2 [16384..]
  __shared__ float part[16][9];                  // head partials [row][wave]

  const int t    = threadIdx.x;
  const int l    = t & 63;
  const int w    = t >> 6;          // 0..7
  const int c15  = l & 15;
  const int quad = l >> 4;          // 0..3
  const int hcol = w * 16 + c15;
  const int kc   = hcol & 31;       // k within chunk for activation writes
  const int chk  = hcol >> 5;       // destination chunk
  const int woff = ((kc >> 3) * 16) * 8 + (kc & 7) + quad * 32; // + q*8 later
  const int r0   = blockIdx.x * 16;

  // z-weight fragments -> registers (80 VGPRs); W1/W2 -> LDS
  short8 Bz[4][5];
  {
    const short8* f8 = (const short8*)wsb;
#pragma unroll
    for (int g = 0; g < 4; ++g)
#pragma unroll
      for (int c = 0; c < 5; ++c)
        Bz[g][c] = f8[((w * 4 + g) * 5 + c) * 64 + l];
    // copy frags 160..223 (64 KB) into LDS, linear
    short8* wm8 = (short8*)wmf;
#pragma unroll
    for (int i = 0; i < 8; ++i)
      wm8[t + i * NT] = f8[160 * 64 + t + i * NT];
  }
  float bzv[4];
#pragma unroll
  for (int g = 0; g < 4; ++g) bzv[g] = bz[g * 128 + hcol];
  const float b1v = b1[hcol], b2v = b2[hcol];
  const float woutv = Wout[hcol];
  const float bout0 = bout[0];

  { // zero hp (h0=0) and xp zero-pad region (k16..31)
    int* p = (int*)&hp[0][0];
    for (int i = t; i < 2048; i += NT) p[i] = 0;
    if (t < 128) ((int*)xp)[128 + t] = 0;
  }
  float cst[4];
#pragma unroll
  for (int q = 0; q < 4; ++q) cst[q] = 0.0f;

  const int gr = t >> 3, gj = t & 7;     // gather role (t < 128)
  float fnext = 0.0f;
  if (t < 128 && gj < 7) fnext = fp.f[gj][(r0 + gr) * T_STEPS];
  __syncthreads();

  for (int step = 0; step < T_STEPS; ++step){
    // ---- gather inputs + deferred head output (p of step-1) ----
    if (t < 128){
      float v;
      if (gj == 7){
        if (step > 0){
          float p = part[gr][0] + part[gr][1] + part[gr][2] + part[gr][3]
                  + part[gr][4] + part[gr][5] + part[gr][6] + part[gr][7] + bout0;
          out[(r0 + gr) * T_STEPS + (step - 1)] = p;
          v = (step < WARM_N) ? irr[(r0 + gr) * WARM_N + step] : p;
        } else {
          v = irr[(r0 + gr) * WARM_N];
        }
      } else {
        v = fnext;
      }
      short hi = f2bf(v);
      xp[gr * 8 + gj]       = hi;                    // k = gj      (hi)
      xp[128 + gr * 8 + gj] = f2bf(v - bf2f(hi));    // k = 8 + gj  (lo)
    }
    __syncthreads();                                  // B1: xp visible

    // prefetch next step's features (hidden behind z-GEMM)
    if (t < 128 && gj < 7 && step + 1 < T_STEPS)
      fnext = fp.f[gj][(r0 + gr) * T_STEPS + step + 1];

    // ---- z = b + [x_hi|x_lo]@[Wi;Wi] + (h_hi+h_lo)@Wh ----
    floatx4 acc[4];
#pragma unroll
    for (int g = 0; g < 4; ++g)
#pragma unroll
      for (int q = 0; q < 4; ++q) acc[g][q] = bzv[g];
    {
      short8 ax = *(const short8*)&xp[l * 8];
#pragma unroll
      for (int g = 0; g < 4; ++g)
        acc[g] = __builtin_amdgcn_mfma_f32_16x16x32_bf16(ax, Bz[g][0], acc[g], 0, 0, 0);
    }
#pragma unroll
    for (int c = 0; c < 4; ++c){
      short8 ah = *(const short8*)&hp[c][l * 8];
      short8 al = *(const short8*)&hp[4 + c][l * 8];
#pragma unroll
      for (int g = 0; g < 4; ++g){
        acc[g] = __builtin_amdgcn_mfma_f32_16x16x32_bf16(ah, Bz[g][1 + c], acc[g], 0, 0, 0);
        acc[g] = __builtin_amdgcn_mfma_f32_16x16x32_bf16(al, Bz[g][1 + c], acc[g], 0, 0, 0);
      }
    }
    __syncthreads();                                  // B2: all h reads done (WAR)

    // ---- gates (fp32 in-lane), c update, h write in place ----
#pragma unroll
    for (int q = 0; q < 4; ++q){
      float zi = acc[0][q], zf = acc[1][q], zg = acc[2][q], zo = acc[3][q];
      float c2 = sigm(zf) * cst[q] + sigm(zi) * tanh_(zg);
      cst[q] = c2;
      float h2 = sigm(zo) * tanh_(c2);
      short hi = f2bf(h2);
      hp[chk][woff + q * 8]     = hi;
      hp[4 + chk][woff + q * 8] = f2bf(h2 - bf2f(hi));
    }
    __syncthreads();                                  // B3: new h visible

    // ---- MLP1: o1 = relu(h@W1 + b1), W1 frags from LDS ----
    floatx4 m1;
#pragma unroll
    for (int q = 0; q < 4; ++q) m1[q] = b1v;
#pragma unroll
    for (int c = 0; c < 4; ++c){
      short8 bf = *(const short8*)&wmf[(w * 4 + c) * 512 + l * 8];
      short8 ah = *(const short8*)&hp[c][l * 8];
      m1 = __builtin_amdgcn_mfma_f32_16x16x32_bf16(ah, bf, m1, 0, 0, 0);
      short8 al = *(const short8*)&hp[4 + c][l * 8];
      m1 = __builtin_amdgcn_mfma_f32_16x16x32_bf16(al, bf, m1, 0, 0, 0);
    }
#pragma unroll
    for (int q = 0; q < 4; ++q)
      o1p[chk][woff + q * 8] = f2bf(fmaxf(m1[q], 0.0f));
    __syncthreads();                                  // B4: o1 visible

    // ---- MLP2 + head partials, W2 frags from LDS ----
    floatx4 m2;
#pragma unroll
    for (int q = 0; q < 4; ++q) m2[q] = b2v;
#pragma unroll
    for (int c = 0; c < 4; ++c){
      short8 bf = *(const short8*)&wmf[16384 + (w * 4 + c) * 512 + l * 8];
      short8 a = *(const short8*)&o1p[c][l * 8];
      m2 = __builtin_amdgcn_mfma_f32_16x16x32_bf16(a, bf, m2, 0, 0, 0);
    }
#pragma unroll
    for (int q = 0; q < 4; ++q){
      float s = fmaxf(m2[q], 0.0f) * woutv;           // o2[row][hcol] * Wout[hcol]
      s += __shfl_down(s, 8, 16);
      s += __shfl_down(s, 4, 16);
      s += __shfl_down(s, 2, 16);
      s += __shfl_down(s, 1, 16);
      if (c15 == 0) part[quad * 4 + q][w] = s;
    }
    __syncthreads();                                  // B5: part visible
  }

  // ---- final step's head output ----
  if (t < 16){
    float p = part[t][0] + part[t][1] + part[t][2] + part[t][3]
            + part[t][4] + part[t][5] + part[t][6] + part[t][7] + bout0;
    out[(r0 + t) * T_STEPS + (T_STEPS - 1)] = p;
  }
}

extern "C" void kernel_launch(void* const* d_in, const int* in_sizes, int n_in,
                              void* d_out, int out_size, void* d_ws, size_t ws_size,
                              hipStream_t stream)
{
  (void)in_sizes; (void)n_in; (void)out_size; (void)ws_size;
  FeatPtrs fp;
  for (int j = 0; j < 7; ++j) fp.f[j] = (const float*)d_in[8 + j];
  const float* irr  = (const float*)d_in[15];
  const float* Wi   = (const float*)d_in[16];
  const float* Wh   = (const float*)d_in[17];
  const float* bz   = (const float*)d_in[18];
  const float* W1   = (const float*)d_in[19];
  const float* b1   = (const float*)d_in[20];
  const float* W2   = (const float*)d_in[21];
  const float* b2   = (const float*)d_in[22];
  const float* Wout = (const float*)d_in[23];
  const float* bout = (const float*)d_in[24];

  short* ws = (short*)d_ws;                        // 224 KB used
  pack_weights<<<dim3(448), dim3(256), 0, stream>>>(Wi, Wh, W1, W2, ws);
  lstm_mfma<<<dim3(512), dim3(NT), 0, stream>>>(
      fp, irr, ws, bz, b1, b2, Wout, bout, (float*)d_out);
}

// Round 7
// 275.796 us; speedup vs baseline: 1.7968x; 1.1045x over previous
//
#include <hip/hip_runtime.h>
#include <hip/hip_fp16.h>

// Fused LSTM(H=128) + MLP head, 16x16x32 **fp16** MFMA, fp32 state.
// 512 blocks x 512 threads (8 waves), 16 rows/block.
// fp16 everywhere on the GEMM paths (weights 2^-11 < bf16 2^-8; all values
// comfortably in fp16 range) -> NO hi/lo split: z-MFMAs 36->20, MLP 12->8.
// Register diet: Wh frags 64 VGPR + W2 frags 16 VGPR (loaded once);
// Wi(x-chunk) + W1 frags in LDS. LDS ~74.9 KB -> 2 blocks/CU target.
// h parity-double-buffered; o1 aliases the read-parity h buffer (WAR-safe:
// z reads it before B2; gates overwrite it only after next step's B1).
// 4 barriers/step. All LDS reads lane-linear ds_read_b128 (conflict-free).

#define T_STEPS 30
#define WARM_N  24
#define NT      512

typedef _Float16 half8 __attribute__((ext_vector_type(8)));
typedef __attribute__((ext_vector_type(8))) short short8;
typedef __attribute__((ext_vector_type(4))) float floatx4;

struct FeatPtrs { const float* f[7]; };

__device__ __forceinline__ short f2h(float v){
  return __half_as_short(__float2half(v));   // RNE
}
__device__ __forceinline__ float sigm(float x){ return 1.0f/(1.0f + __expf(-x)); }
__device__ __forceinline__ float tanh_(float x){ return 1.0f - 2.0f/(__expf(2.0f*x) + 1.0f); }

// ---------------- weight pack (fp16) ----------------
// Frag = 64 lanes x 8 halves = 512 elems; elem (l,j): B[k=(l>>4)*8+j][col].
// shorts offsets:
//  Z  @ 0      : Wh frags [w 0..7][g 0..3][c 0..3], col = g*128+w*16+(l&15),
//                row = c*32 + k
//  X  @ 65536  : Wi frags [w][g], K=32 padded: k<8 -> Wi[k][col], else 0
//  W1 @ 81920  : [w][c 0..3], B = W1[c*32+k][w*16+(l&15)]
//  W2 @ 98304  : [w][c 0..3], same with W2
__global__ void pack_weights(const float* __restrict__ Wi, const float* __restrict__ Wh,
                             const float* __restrict__ W1, const float* __restrict__ W2,
                             short* __restrict__ ws)
{
  int idx = blockIdx.x * 256 + threadIdx.x;
  if (idx >= 114688) return;
  int r = idx & 511;
  int l = r >> 3, j = r & 7;
  int k   = ((l >> 4) << 3) + j;          // 0..31
  int n16 = l & 15;
  float v;
  if (idx < 65536){
    int f = idx >> 9;                     // 0..127
    int w = f >> 4, g = (f >> 2) & 3, c = f & 3;
    v = Wh[(c * 32 + k) * 512 + g * 128 + w * 16 + n16];
  } else if (idx < 81920){
    int f = (idx - 65536) >> 9;           // 0..31
    int w = f >> 2, g = f & 3;
    v = (k < 8) ? Wi[k * 512 + g * 128 + w * 16 + n16] : 0.0f;
  } else if (idx < 98304){
    int f = (idx - 81920) >> 9;
    int w = f >> 2, c = f & 3;
    v = W1[(c * 32 + k) * 128 + w * 16 + n16];
  } else {
    int f = (idx - 98304) >> 9;
    int w = f >> 2, c = f & 3;
    v = W2[(c * 32 + k) * 128 + w * 16 + n16];
  }
  ws[idx] = f2h(v);
}

// ---------------- main kernel ----------------
// fragment-contiguous chunk: pos of (row,k) = ((k>>3)*16 + row)*8 + (k&7)
__global__ __launch_bounds__(NT, 2)
void lstm_mfma(FeatPtrs fp, const float* __restrict__ irr,
               const short* __restrict__ wsb,
               const float* __restrict__ bz, const float* __restrict__ b1,
               const float* __restrict__ b2, const float* __restrict__ Wout,
               const float* __restrict__ bout, float* __restrict__ out)
{
  __shared__ __align__(16) short xb[16384];      // Wi x-chunk B-frags (32 KB)
  __shared__ __align__(16) short wm1[16384];     // W1 B-frags (32 KB)
  __shared__ __align__(16) short xp[512];        // x A-panel (k0-7 data, 8-31 zero)
  __shared__ __align__(16) short hp[2][4][512];  // h panels, parity double-buffer
  __shared__ float part[16][9];                  // head partials [row][wave]

  const int t    = threadIdx.x;
  const int l    = t & 63;
  const int w    = t >> 6;          // 0..7
  const int c15  = l & 15;
  const int quad = l >> 4;          // 0..3
  const int hcol = w * 16 + c15;
  const int kc   = hcol & 31;
  const int chk  = hcol >> 5;       // 0..3
  const int woff = ((kc >> 3) * 16) * 8 + (kc & 7) + quad * 32; // + q*8
  const int r0   = blockIdx.x * 16;

  // Wh frags (64 VGPR) + W2 frags (16 VGPR, loaded once)
  half8 Bz[4][4], W2r[4];
  {
    const half8* f8 = (const half8*)wsb;
#pragma unroll
    for (int g = 0; g < 4; ++g)
#pragma unroll
      for (int c = 0; c < 4; ++c)
        Bz[g][c] = f8[((w * 4 + g) * 4 + c) * 64 + l];
#pragma unroll
    for (int c = 0; c < 4; ++c)
      W2r[c] = f8[12288 + (w * 4 + c) * 64 + l];
    // X frags (shorts 65536..81919) and W1 frags (81920..98303) -> LDS
    const short8* s8 = (const short8*)wsb;
#pragma unroll
    for (int i = 0; i < 4; ++i){
      ((short8*)xb)[t + i * NT]  = s8[8192  + t + i * NT];
      ((short8*)wm1)[t + i * NT] = s8[10240 + t + i * NT];
    }
  }
  float bzv[4];
#pragma unroll
  for (int g = 0; g < 4; ++g) bzv[g] = bz[g * 128 + hcol];
  const float b1v = b1[hcol], b2v = b2[hcol];
  const float woutv = Wout[hcol];
  const float bout0 = bout[0];

  { // zero hp[0] (h0 = 0) and xp pad region (k8..31)
    int* p = (int*)&hp[0][0][0];
    for (int i = t; i < 1024; i += NT) p[i] = 0;
    if (t < 192) ((int*)xp)[64 + t] = 0;
  }
  float cst[4];
#pragma unroll
  for (int q = 0; q < 4; ++q) cst[q] = 0.0f;

  const int gr = t >> 3, gj = t & 7;     // gather role (t < 128)
  float fnext = 0.0f;
  if (t < 128 && gj < 7) fnext = fp.f[gj][(r0 + gr) * T_STEPS];
  __syncthreads();

  for (int step = 0; step < T_STEPS; ++step){
    // ---- gather inputs (fp16) + deferred head output (p of step-1) ----
    if (t < 128){
      float v;
      if (gj == 7){
        if (step > 0){
          float p = part[gr][0] + part[gr][1] + part[gr][2] + part[gr][3]
                  + part[gr][4] + part[gr][5] + part[gr][6] + part[gr][7] + bout0;
          out[(r0 + gr) * T_STEPS + (step - 1)] = p;
          v = (step < WARM_N) ? irr[(r0 + gr) * WARM_N + step] : p;
        } else {
          v = irr[(r0 + gr) * WARM_N];
        }
      } else {
        v = fnext;
      }
      xp[gr * 8 + gj] = f2h(v);                      // pos(row=gr, k=gj)
    }
    __syncthreads();                                  // B1

    if (t < 128 && gj < 7 && step + 1 < T_STEPS)
      fnext = fp.f[gj][(r0 + gr) * T_STEPS + step + 1];

    const int rp = step & 1, wp = rp ^ 1;

    // ---- z = b + x@Wi + h@Wh ----
    floatx4 acc[4];
#pragma unroll
    for (int g = 0; g < 4; ++g)
#pragma unroll
      for (int q = 0; q < 4; ++q) acc[g][q] = bzv[g];
    {
      half8 ax = *(const half8*)&xp[l * 8];
#pragma unroll
      for (int g = 0; g < 4; ++g){
        half8 bx = *(const half8*)&xb[((w * 4 + g) << 9) + l * 8];
        acc[g] = __builtin_amdgcn_mfma_f32_16x16x32_f16(ax, bx, acc[g], 0, 0, 0);
      }
    }
#pragma unroll
    for (int c = 0; c < 4; ++c){
      half8 ah = *(const half8*)&hp[rp][c][l * 8];
#pragma unroll
      for (int g = 0; g < 4; ++g)
        acc[g] = __builtin_amdgcn_mfma_f32_16x16x32_f16(ah, Bz[g][c], acc[g], 0, 0, 0);
    }

    // ---- gates (fp32 in-lane), c update, h write (parity wp) ----
#pragma unroll
    for (int q = 0; q < 4; ++q){
      float zi = acc[0][q], zf = acc[1][q], zg = acc[2][q], zo = acc[3][q];
      float c2 = sigm(zf) * cst[q] + sigm(zi) * tanh_(zg);
      cst[q] = c2;
      float h2 = sigm(zo) * tanh_(c2);
      hp[wp][chk][woff + q * 8] = f2h(h2);
    }
    __syncthreads();                                  // B2: h reads done + new h visible

    // ---- MLP1: o1 = relu(h@W1 + b1); o1 -> hp[rp] (aliased, safe) ----
    floatx4 m1;
#pragma unroll
    for (int q = 0; q < 4; ++q) m1[q] = b1v;
#pragma unroll
    for (int c = 0; c < 4; ++c){
      half8 bf = *(const half8*)&wm1[((w * 4 + c) << 9) + l * 8];
      half8 ah = *(const half8*)&hp[wp][c][l * 8];
      m1 = __builtin_amdgcn_mfma_f32_16x16x32_f16(ah, bf, m1, 0, 0, 0);
    }
#pragma unroll
    for (int q = 0; q < 4; ++q)
      hp[rp][chk][woff + q * 8] = f2h(fmaxf(m1[q], 0.0f));
    __syncthreads();                                  // B3: o1 visible

    // ---- MLP2 (W2 in regs) + head partials ----
    floatx4 m2;
#pragma unroll
    for (int q = 0; q < 4; ++q) m2[q] = b2v;
#pragma unroll
    for (int c = 0; c < 4; ++c){
      half8 a = *(const half8*)&hp[rp][c][l * 8];
      m2 = __builtin_amdgcn_mfma_f32_16x16x32_f16(a, W2r[c], m2, 0, 0, 0);
    }
#pragma unroll
    for (int q = 0; q < 4; ++q){
      float s = fmaxf(m2[q], 0.0f) * woutv;           // o2[row][hcol]*Wout[hcol]
      s += __shfl_down(s, 8, 16);
      s += __shfl_down(s, 4, 16);
      s += __shfl_down(s, 2, 16);
      s += __shfl_down(s, 1, 16);
      if (c15 == 0) part[quad * 4 + q][w] = s;
    }
    __syncthreads();                                  // B4: part visible
  }

  // ---- final step's head output ----
  if (t < 16){
    float p = part[t][0] + part[t][1] + part[t][2] + part[t][3]
            + part[t][4] + part[t][5] + part[t][6] + part[t][7] + bout0;
    out[(r0 + t) * T_STEPS + (T_STEPS - 1)] = p;
  }
}

extern "C" void kernel_launch(void* const* d_in, const int* in_sizes, int n_in,
                              void* d_out, int out_size, void* d_ws, size_t ws_size,
                              hipStream_t stream)
{
  (void)in_sizes; (void)n_in; (void)out_size; (void)ws_size;
  FeatPtrs fp;
  for (int j = 0; j < 7; ++j) fp.f[j] = (const float*)d_in[8 + j];
  const float* irr  = (const float*)d_in[15];
  const float* Wi   = (const float*)d_in[16];
  const float* Wh   = (const float*)d_in[17];
  const float* bz   = (const float*)d_in[18];
  const float* W1   = (const float*)d_in[19];
  const float* b1   = (const float*)d_in[20];
  const float* W2   = (const float*)d_in[21];
  const float* b2   = (const float*)d_in[22];
  const float* Wout = (const float*)d_in[23];
  const float* bout = (const float*)d_in[24];

  short* ws = (short*)d_ws;                        // 224 KB used
  pack_weights<<<dim3(448), dim3(256), 0, stream>>>(Wi, Wh, W1, W2, ws);
  lstm_mfma<<<dim3(512), dim3(NT), 0, stream>>>(
      fp, irr, ws, bz, b1, b2, Wout, bout, (float*)d_out);
}